// Round 1
// baseline (9911.979 us; speedup 1.0000x reference)
//
#include <hip/hip_runtime.h>
#include <math.h>
#include <stdint.h>

#define BATCH 4096
#define MCAND 50
#define NTOP 32
#define HID 100

__device__ __forceinline__ uint32_t rotl32(uint32_t v, int d){ return (v<<d)|(v>>(32-d)); }

// JAX threefry2x32 core (20 rounds, 5 key injections)
__device__ __forceinline__ void tf2x32(uint32_t k0, uint32_t k1, uint32_t x0, uint32_t x1,
                                       uint32_t &o0, uint32_t &o1){
  uint32_t k2 = k0 ^ k1 ^ 0x1BD11BDAu;
  x0 += k0; x1 += k1;
#define RND(r) { x0 += x1; x1 = rotl32(x1,(r)); x1 ^= x0; }
  RND(13) RND(15) RND(26) RND(6)
  x0 += k1; x1 += k2 + 1u;
  RND(17) RND(29) RND(16) RND(24)
  x0 += k2; x1 += k0 + 2u;
  RND(13) RND(15) RND(26) RND(6)
  x0 += k0; x1 += k1 + 3u;
  RND(17) RND(29) RND(16) RND(24)
  x0 += k1; x1 += k2 + 4u;
  RND(13) RND(15) RND(26) RND(6)
  x0 += k2; x1 += k0 + 5u;
#undef RND
  o0 = x0; o1 = x1;
}

// XLA ErfInv32 (Giles). w = -log1p(-x*x)
__device__ __forceinline__ float erfinv32(float x){
  float w = -log1pf(-x*x);
  float p;
  if (w < 5.0f){
    w = w - 2.5f;
    p = 2.81022636e-08f;
    p = fmaf(p, w, 3.43273939e-07f);
    p = fmaf(p, w, -3.5233877e-06f);
    p = fmaf(p, w, -4.39150654e-06f);
    p = fmaf(p, w, 0.00021858087f);
    p = fmaf(p, w, -0.00125372503f);
    p = fmaf(p, w, -0.00417768164f);
    p = fmaf(p, w, 0.246640727f);
    p = fmaf(p, w, 1.50140941f);
  } else {
    w = sqrtf(w) - 3.0f;
    p = -0.000200214257f;
    p = fmaf(p, w, 0.000100950558f);
    p = fmaf(p, w, 0.00134934322f);
    p = fmaf(p, w, -0.00367342844f);
    p = fmaf(p, w, 0.00573950773f);
    p = fmaf(p, w, -0.0076224613f);
    p = fmaf(p, w, 0.00943887047f);
    p = fmaf(p, w, 1.00167406f);
    p = fmaf(p, w, 2.83297682f);
  }
  return p*x;
}

__global__ __launch_bounds__(256, 2) void cem_kernel(
    const float* __restrict__ states, const float* __restrict__ W1,
    const float* __restrict__ b1,     const float* __restrict__ W2,
    const float* __restrict__ b2,     const float* __restrict__ W3,
    const float* __restrict__ b3,     float* __restrict__ out)
{
  __shared__ __align__(16) float sW2T[HID*HID];   // W2T[j][k], stride 100
  __shared__ __align__(16) float sH1[MCAND*HID];  // h1[c][k], stride 100
  __shared__ float sPart[MCAND*26];
  __shared__ float sSW[HID], sW13[HID], sB2[HID], sW3[HID];
  __shared__ float sA[MCAND];
  __shared__ uint32_t sKeys[198];
  __shared__ float sB3;

  const int tid = threadIdx.x;
  const int b   = blockIdx.x;
  const float s0 = states[2*b], s1 = states[2*b+1];

  // stage W2 transposed into LDS
  for (int f = tid; f < HID*HID; f += 256){
    int j = f / HID, k = f - j*HID;
    sW2T[f] = W2[k*HID + j];
  }
  if (tid < HID){
    float w0 = W1[tid], w1 = W1[HID+tid];
    sSW[tid]  = fmaf(s0, w0, fmaf(s1, w1, b1[tid]));
    sW13[tid] = W1[2*HID+tid];
    sB2[tid]  = b2[tid];
    sW3[tid]  = W3[tid];
  }
  if (tid == 0) sB3 = b3[0];

  // key schedule: key(42) = (0,42); split -> k0=(A0,B0), kloop=(A1,B1)
  if (tid < 99){
    uint32_t A0,A1,B0,B1;
    tf2x32(0u,42u,0u,2u,A0,A1);
    tf2x32(0u,42u,1u,3u,B0,B1);
    uint32_t o0,o1;
    tf2x32(A1,B1,(uint32_t)tid,(uint32_t)(99+tid),o0,o1);
    sKeys[tid]    = o0;
    sKeys[99+tid] = o1;
    if (tid < MCAND){
      // iteration-0 angles: uniform[0,1) from k0=(A0,B0)
      uint32_t gidx = (uint32_t)b*MCAND + (uint32_t)tid;
      uint32_t r0,r1,bits;
      if (gidx < 102400u){ tf2x32(A0,B0,gidx,gidx+102400u,r0,r1); bits = r0; }
      else               { tf2x32(A0,B0,gidx-102400u,gidx,r0,r1); bits = r1; }
      sA[tid] = __uint_as_float((bits>>9) | 0x3f800000u) - 1.0f;
    }
  }
  __syncthreads();

  const int cg = tid / 25;        // candidate group 0..9 (tid<250)
  const int jg = tid - cg*25;     // j group 0..24
  const bool gemmActive = (tid < 250);
  const float MINV = -0x1.fffffep-1f;   // nextafter(-1,0)
  const float SQRT2 = 0x1.6a09e6p+0f;   // fp32 sqrt(2)

#pragma unroll 1
  for (int t = 0; t < 99; ++t){
    // ---- phase 1: h1[c][k] = relu(sW[k] + a_c * W1[2][k]) ----
    for (int f = tid; f < MCAND*HID; f += 256){
      int c = f / HID; int k = f - c*HID;
      sH1[f] = fmaxf(fmaf(sA[c], sW13[k], sSW[k]), 0.0f);
    }
    __syncthreads();

    // ---- phase 2: h2 = relu(h1 @ W2 + b2); partial q = h2 .* W3 ----
    if (gemmActive){
      float acc[5][4];
#pragma unroll
      for (int i=0;i<5;++i)
#pragma unroll
        for (int jj=0;jj<4;++jj) acc[i][jj] = 0.0f;

#pragma unroll 5
      for (int k4 = 0; k4 < 25; ++k4){
        float4 av[5]; float4 bv[4];
#pragma unroll
        for (int i=0;i<5;++i)
          av[i] = *(const float4*)&sH1[(5*cg+i)*HID + 4*k4];
#pragma unroll
        for (int jj=0;jj<4;++jj)
          bv[jj] = *(const float4*)&sW2T[(jg+25*jj)*HID + 4*k4];
#pragma unroll
        for (int i=0;i<5;++i)
#pragma unroll
          for (int jj=0;jj<4;++jj){
            acc[i][jj] = fmaf(av[i].x, bv[jj].x, acc[i][jj]);
            acc[i][jj] = fmaf(av[i].y, bv[jj].y, acc[i][jj]);
            acc[i][jj] = fmaf(av[i].z, bv[jj].z, acc[i][jj]);
            acc[i][jj] = fmaf(av[i].w, bv[jj].w, acc[i][jj]);
          }
      }
#pragma unroll
      for (int i=0;i<5;++i){
        float partial = 0.0f;
#pragma unroll
        for (int jj=0;jj<4;++jj){
          int j = jg + 25*jj;
          float h2 = fmaxf(acc[i][jj] + sB2[j], 0.0f);
          partial = fmaf(h2, sW3[j], partial);
        }
        sPart[(5*cg+i)*26 + jg] = partial;
      }
    }
    __syncthreads();

    // ---- phase 3: wave 0 reduces q, top-32 stats, next angles ----
    if (tid < 64){
      float q = -INFINITY;
      if (tid < MCAND){
        float s = sB3;
#pragma unroll
        for (int r = 0; r < 25; ++r) s += sPart[tid*26 + r];
        q = s;
      }
      // stable rank (permutation -> exactly 32 elites; ties value-identical)
      int rank = 0;
      for (int s = 0; s < MCAND; ++s){
        float qs = __shfl(q, s, 64);
        if (qs > q || (qs == q && s < tid)) rank++;
      }
      bool elite = (tid < MCAND) && (rank < NTOP);
      float sv = elite ? q : 0.0f;
#pragma unroll
      for (int off = 32; off >= 1; off >>= 1) sv += __shfl_xor(sv, off, 64);
      float mu = sv / 32.0f;
      // two-pass std, ddof=1
      float dv = elite ? (q - mu) : 0.0f;
      float s2 = dv*dv;
#pragma unroll
      for (int off = 32; off >= 1; off >>= 1) s2 += __shfl_xor(s2, off, 64);
      float stdv = sqrtf(s2 / 31.0f);

      if (t == 98){
        if (tid == 0) out[b] = mu * 6.2831854820251465f;  // fp32(2*pi)
      } else if (tid < MCAND){
        uint32_t kk0 = sKeys[2*t], kk1 = sKeys[2*t+1];
        uint32_t gidx = (uint32_t)b*MCAND + (uint32_t)tid;
        uint32_t r0,r1,bits;
        if (gidx < 102400u){ tf2x32(kk0,kk1,gidx,gidx+102400u,r0,r1); bits = r0; }
        else               { tf2x32(kk0,kk1,gidx-102400u,gidx,r0,r1); bits = r1; }
        float fl = __uint_as_float((bits>>9) | 0x3f800000u) - 1.0f;
        float u  = fl*2.0f + MINV;      // scale (hi-lo) rounds exactly to 2.0f
        u = fmaxf(MINV, u);
        float e = SQRT2 * erfinv32(u);
        sA[tid] = mu + stdv * e;
      }
    }
    __syncthreads();
  }
}

extern "C" void kernel_launch(void* const* d_in, const int* in_sizes, int n_in,
                              void* d_out, int out_size, void* d_ws, size_t ws_size,
                              hipStream_t stream) {
  const float* states = (const float*)d_in[0];
  const float* W1     = (const float*)d_in[1];
  const float* b1     = (const float*)d_in[2];
  const float* W2     = (const float*)d_in[3];
  const float* b2     = (const float*)d_in[4];
  const float* W3     = (const float*)d_in[5];
  const float* b3     = (const float*)d_in[6];
  float* out = (float*)d_out;
  hipLaunchKernelGGL(cem_kernel, dim3(BATCH), dim3(256), 0, stream,
                     states, W1, b1, W2, b2, W3, b3, out);
}

// Round 2
// 6972.412 us; speedup vs baseline: 1.4216x; 1.4216x over previous
//
#include <hip/hip_runtime.h>
#include <math.h>
#include <stdint.h>

#define BATCH 4096
#define MCAND 50
#define NTOP 32
#define HID 100

typedef __attribute__((ext_vector_type(8))) short bf16x8;
typedef __attribute__((ext_vector_type(16))) float f32x16;

union FragU { bf16x8 v; unsigned short s[8]; };

__device__ __forceinline__ uint32_t rotl32(uint32_t v, int d){ return (v<<d)|(v>>(32-d)); }

// JAX threefry2x32 core (20 rounds, 5 key injections)
__device__ __forceinline__ void tf2x32(uint32_t k0, uint32_t k1, uint32_t x0, uint32_t x1,
                                       uint32_t &o0, uint32_t &o1){
  uint32_t k2 = k0 ^ k1 ^ 0x1BD11BDAu;
  x0 += k0; x1 += k1;
#define RND(r) { x0 += x1; x1 = rotl32(x1,(r)); x1 ^= x0; }
  RND(13) RND(15) RND(26) RND(6)
  x0 += k1; x1 += k2 + 1u;
  RND(17) RND(29) RND(16) RND(24)
  x0 += k2; x1 += k0 + 2u;
  RND(13) RND(15) RND(26) RND(6)
  x0 += k0; x1 += k1 + 3u;
  RND(17) RND(29) RND(16) RND(24)
  x0 += k1; x1 += k2 + 4u;
  RND(13) RND(15) RND(26) RND(6)
  x0 += k2; x1 += k0 + 5u;
#undef RND
  o0 = x0; o1 = x1;
}

// XLA ErfInv32 (Giles). w = -log1p(-x*x)
__device__ __forceinline__ float erfinv32(float x){
  float w = -log1pf(-x*x);
  float p;
  if (w < 5.0f){
    w = w - 2.5f;
    p = 2.81022636e-08f;
    p = fmaf(p, w, 3.43273939e-07f);
    p = fmaf(p, w, -3.5233877e-06f);
    p = fmaf(p, w, -4.39150654e-06f);
    p = fmaf(p, w, 0.00021858087f);
    p = fmaf(p, w, -0.00125372503f);
    p = fmaf(p, w, -0.00417768164f);
    p = fmaf(p, w, 0.246640727f);
    p = fmaf(p, w, 1.50140941f);
  } else {
    w = sqrtf(w) - 3.0f;
    p = -0.000200214257f;
    p = fmaf(p, w, 0.000100950558f);
    p = fmaf(p, w, 0.00134934322f);
    p = fmaf(p, w, -0.00367342844f);
    p = fmaf(p, w, 0.00573950773f);
    p = fmaf(p, w, -0.0076224613f);
    p = fmaf(p, w, 0.00943887047f);
    p = fmaf(p, w, 1.00167406f);
    p = fmaf(p, w, 2.83297682f);
  }
  return p*x;
}

// exact 3-way bf16 split of an fp32 value (truncation): x == hi+mid+lo exactly
__device__ __forceinline__ void split3(float x, unsigned short &h, unsigned short &m,
                                       unsigned short &l){
  uint32_t xb = __float_as_uint(x);
  h = (unsigned short)(xb >> 16);
  float r = x - __uint_as_float(xb & 0xFFFF0000u);
  uint32_t rb = __float_as_uint(r);
  m = (unsigned short)(rb >> 16);
  float r2 = r - __uint_as_float(rb & 0xFFFF0000u);
  l = (unsigned short)(__float_as_uint(r2) >> 16);
}

#define MFMA(a,b,c) __builtin_amdgcn_mfma_f32_32x32x16_bf16((a),(b),(c),0,0,0)

// LDS A-planes: 3 planes x 64 rows x 120 bf16, stride 120 (240B = 15 quads, odd)
#define AROW 120
#define APLANE (64*AROW)

__global__ __launch_bounds__(256, 3) void cem_kernel(
    const float* __restrict__ states, const float* __restrict__ W1,
    const float* __restrict__ b1,     const float* __restrict__ W2,
    const float* __restrict__ b2,     const float* __restrict__ W3,
    const float* __restrict__ b3,     float* __restrict__ out)
{
  __shared__ __align__(16) unsigned short sApl[3*APLANE]; // 46080 B
  __shared__ float qbuf[4][64];
  __shared__ float sSW[HID], sW13[HID];
  __shared__ float sA[MCAND];
  __shared__ uint32_t sKeys[198];
  __shared__ float sB3;

  const int tid  = threadIdx.x;
  const int b    = blockIdx.x;
  const int wv   = tid >> 6;
  const int lane = tid & 63;
  const int half = lane >> 5;
  const int col  = lane & 31;
  const int n    = wv*32 + col;    // output-neuron column for layer 2

  const float s0 = states[2*b], s1 = states[2*b+1];

  // zero-init A planes (pads must stay zero)
  for (int f = tid; f < (3*APLANE)/2; f += 256) ((unsigned int*)sApl)[f] = 0u;

  if (tid < HID){
    float w0 = W1[tid], w1 = W1[HID+tid];
    sSW[tid]  = fmaf(s0, w0, fmaf(s1, w1, b1[tid]));
    sW13[tid] = W1[2*HID+tid];
  }
  if (tid == 0) sB3 = b3[0];

  // per-lane epilogue constants
  const float bn2 = (n < HID) ? b2[n] : 0.0f;
  const float wn3 = (n < HID) ? W3[n] : 0.0f;

  // one-time: build static W2 B-fragments in registers (3 exact bf16 planes)
  bf16x8 Bfh[7], Bfm[7], Bfl[7];
#pragma unroll
  for (int ks = 0; ks < 7; ++ks){
    FragU fh, fm, fl;
#pragma unroll
    for (int i = 0; i < 8; ++i){
      int k = ks*16 + half*8 + i;
      float w = (k < HID && n < HID) ? W2[k*HID + n] : 0.0f;
      split3(w, fh.s[i], fm.s[i], fl.s[i]);
    }
    Bfh[ks] = fh.v; Bfm[ks] = fm.v; Bfl[ks] = fl.v;
  }

  // key schedule: key(42) = (0,42); split -> k0=(A0,B0), kloop=(A1,B1)
  if (tid < 99){
    uint32_t A0,A1,B0,B1;
    tf2x32(0u,42u,0u,2u,A0,A1);
    tf2x32(0u,42u,1u,3u,B0,B1);
    uint32_t o0,o1;
    tf2x32(A1,B1,(uint32_t)tid,(uint32_t)(99+tid),o0,o1);
    sKeys[tid]    = o0;
    sKeys[99+tid] = o1;
    if (tid < MCAND){
      uint32_t gidx = (uint32_t)b*MCAND + (uint32_t)tid;
      uint32_t r0,r1,bits;
      if (gidx < 102400u){ tf2x32(A0,B0,gidx,gidx+102400u,r0,r1); bits = r0; }
      else               { tf2x32(A0,B0,gidx-102400u,gidx,r0,r1); bits = r1; }
      sA[tid] = __uint_as_float((bits>>9) | 0x3f800000u) - 1.0f;
    }
  }
  __syncthreads();

  const float MINV = -0x1.fffffep-1f;   // nextafter(-1,0)
  const float SQRT2 = 0x1.6a09e6p+0f;   // fp32 sqrt(2)

#pragma unroll 1
  for (int t = 0; t < 99; ++t){
    // ---- phase 1: h1[c][k] = relu(sSW[k] + a_c*sW13[k]); exact 3-split to planes ----
    for (int f = tid; f < MCAND*(HID/2); f += 256){
      int c  = f / (HID/2);
      int k  = (f - c*(HID/2)) * 2;
      float a = sA[c];
      float2 swp  = *(const float2*)&sSW[k];
      float2 w13p = *(const float2*)&sW13[k];
      float v0 = fmaxf(fmaf(a, w13p.x, swp.x), 0.0f);
      float v1 = fmaxf(fmaf(a, w13p.y, swp.y), 0.0f);
      unsigned short h0,m0,l0,h1_,m1,l1;
      split3(v0, h0, m0, l0);
      split3(v1, h1_, m1, l1);
      int base = c*AROW + k;
      *(unsigned int*)&sApl[0*APLANE + base] = (unsigned int)h0 | ((unsigned int)h1_<<16);
      *(unsigned int*)&sApl[1*APLANE + base] = (unsigned int)m0 | ((unsigned int)m1 <<16);
      *(unsigned int*)&sApl[2*APLANE + base] = (unsigned int)l0 | ((unsigned int)l1 <<16);
    }
    __syncthreads();

    // ---- phase 2: MFMA GEMM h2 = relu(h1@W2+b2), q-partials per column-tile ----
    {
      f32x16 acc0, acc1;
#pragma unroll
      for (int r = 0; r < 16; ++r){ acc0[r] = 0.0f; acc1[r] = 0.0f; }

#pragma unroll
      for (int ks = 0; ks < 7; ++ks){
        const int kb = ks*16 + half*8;
        const int r0 = col*AROW + kb;
        const int r1 = (32+col)*AROW + kb;
        bf16x8 a0h = *(const bf16x8*)&sApl[0*APLANE + r0];
        bf16x8 a1h = *(const bf16x8*)&sApl[0*APLANE + r1];
        bf16x8 a0m = *(const bf16x8*)&sApl[1*APLANE + r0];
        bf16x8 a1m = *(const bf16x8*)&sApl[1*APLANE + r1];
        bf16x8 a0l = *(const bf16x8*)&sApl[2*APLANE + r0];
        bf16x8 a1l = *(const bf16x8*)&sApl[2*APLANE + r1];
        acc0 = MFMA(a0h, Bfh[ks], acc0);
        acc1 = MFMA(a1h, Bfh[ks], acc1);
        acc0 = MFMA(a0m, Bfh[ks], acc0);
        acc1 = MFMA(a1m, Bfh[ks], acc1);
        acc0 = MFMA(a0h, Bfm[ks], acc0);
        acc1 = MFMA(a1h, Bfm[ks], acc1);
        acc0 = MFMA(a0m, Bfm[ks], acc0);
        acc1 = MFMA(a1m, Bfm[ks], acc1);
        acc0 = MFMA(a0l, Bfh[ks], acc0);
        acc1 = MFMA(a1l, Bfh[ks], acc1);
        acc0 = MFMA(a0h, Bfl[ks], acc0);
        acc1 = MFMA(a1h, Bfl[ks], acc1);
      }

      // epilogue: h2 = relu(acc+b2[n]); qpart = h2*W3[n]; reduce over 32 cols
#pragma unroll
      for (int mt = 0; mt < 2; ++mt){
        float qp[16];
#pragma unroll
        for (int r = 0; r < 16; ++r){
          float av = mt ? acc1[r] : acc0[r];
          qp[r] = fmaxf(av + bn2, 0.0f) * wn3;
        }
#pragma unroll
        for (int off = 1; off <= 16; off <<= 1){
#pragma unroll
          for (int r = 0; r < 16; ++r) qp[r] += __shfl_xor(qp[r], off, 64);
        }
        if (col == 0){
#pragma unroll
          for (int r = 0; r < 16; ++r){
            int row = (r&3) + 8*(r>>2) + 4*half + mt*32;
            qbuf[wv][row] = qp[r];
          }
        }
      }
    }
    __syncthreads();

    // ---- phase 3: wave 0 reduces q, top-32 stats, next angles ----
    if (tid < 64){
      float q = -INFINITY;
      if (tid < MCAND){
        q = qbuf[0][tid] + qbuf[1][tid] + qbuf[2][tid] + qbuf[3][tid] + sB3;
      }
      // stable rank (permutation -> exactly 32 elites; ties value-identical)
      int rank = 0;
      for (int s = 0; s < MCAND; ++s){
        float qs = __shfl(q, s, 64);
        if (qs > q || (qs == q && s < tid)) rank++;
      }
      bool elite = (tid < MCAND) && (rank < NTOP);
      float sv = elite ? q : 0.0f;
#pragma unroll
      for (int off = 32; off >= 1; off >>= 1) sv += __shfl_xor(sv, off, 64);
      float mu = sv / 32.0f;
      float dv = elite ? (q - mu) : 0.0f;
      float s2 = dv*dv;
#pragma unroll
      for (int off = 32; off >= 1; off >>= 1) s2 += __shfl_xor(s2, off, 64);
      float stdv = sqrtf(s2 / 31.0f);

      if (t == 98){
        if (tid == 0) out[b] = mu * 6.2831854820251465f;  // fp32(2*pi)
      } else if (tid < MCAND){
        uint32_t kk0 = sKeys[2*t], kk1 = sKeys[2*t+1];
        uint32_t gidx = (uint32_t)b*MCAND + (uint32_t)tid;
        uint32_t r0,r1,bits;
        if (gidx < 102400u){ tf2x32(kk0,kk1,gidx,gidx+102400u,r0,r1); bits = r0; }
        else               { tf2x32(kk0,kk1,gidx-102400u,gidx,r0,r1); bits = r1; }
        float fl = __uint_as_float((bits>>9) | 0x3f800000u) - 1.0f;
        float u  = fl*2.0f + MINV;
        u = fmaxf(MINV, u);
        float e = SQRT2 * erfinv32(u);
        sA[tid] = mu + stdv * e;
      }
    }
    __syncthreads();
  }
}

extern "C" void kernel_launch(void* const* d_in, const int* in_sizes, int n_in,
                              void* d_out, int out_size, void* d_ws, size_t ws_size,
                              hipStream_t stream) {
  const float* states = (const float*)d_in[0];
  const float* W1     = (const float*)d_in[1];
  const float* b1     = (const float*)d_in[2];
  const float* W2     = (const float*)d_in[3];
  const float* b2     = (const float*)d_in[4];
  const float* W3     = (const float*)d_in[5];
  const float* b3     = (const float*)d_in[6];
  float* out = (float*)d_out;
  hipLaunchKernelGGL(cem_kernel, dim3(BATCH), dim3(256), 0, stream,
                     states, W1, b1, W2, b2, W3, b3, out);
}

// Round 3
// 5772.614 us; speedup vs baseline: 1.7171x; 1.2078x over previous
//
#include <hip/hip_runtime.h>
#include <math.h>
#include <stdint.h>

#define BATCH 4096
#define MCAND 50
#define NTOP 32
#define HID 100

typedef __attribute__((ext_vector_type(8))) short bf16x8;
typedef __attribute__((ext_vector_type(16))) float f32x16;

union FragU { bf16x8 v; unsigned short s[8]; };

__device__ __forceinline__ uint32_t rotl32(uint32_t v, int d){ return (v<<d)|(v>>(32-d)); }

// JAX threefry2x32 core (20 rounds, 5 key injections)
__device__ __forceinline__ void tf2x32(uint32_t k0, uint32_t k1, uint32_t x0, uint32_t x1,
                                       uint32_t &o0, uint32_t &o1){
  uint32_t k2 = k0 ^ k1 ^ 0x1BD11BDAu;
  x0 += k0; x1 += k1;
#define RND(r) { x0 += x1; x1 = rotl32(x1,(r)); x1 ^= x0; }
  RND(13) RND(15) RND(26) RND(6)
  x0 += k1; x1 += k2 + 1u;
  RND(17) RND(29) RND(16) RND(24)
  x0 += k2; x1 += k0 + 2u;
  RND(13) RND(15) RND(26) RND(6)
  x0 += k0; x1 += k1 + 3u;
  RND(17) RND(29) RND(16) RND(24)
  x0 += k1; x1 += k2 + 4u;
  RND(13) RND(15) RND(26) RND(6)
  x0 += k2; x1 += k0 + 5u;
#undef RND
  o0 = x0; o1 = x1;
}

// XLA ErfInv32 (Giles). w = -log1p(-x*x)
__device__ __forceinline__ float erfinv32(float x){
  float w = -log1pf(-x*x);
  float p;
  if (w < 5.0f){
    w = w - 2.5f;
    p = 2.81022636e-08f;
    p = fmaf(p, w, 3.43273939e-07f);
    p = fmaf(p, w, -3.5233877e-06f);
    p = fmaf(p, w, -4.39150654e-06f);
    p = fmaf(p, w, 0.00021858087f);
    p = fmaf(p, w, -0.00125372503f);
    p = fmaf(p, w, -0.00417768164f);
    p = fmaf(p, w, 0.246640727f);
    p = fmaf(p, w, 1.50140941f);
  } else {
    w = sqrtf(w) - 3.0f;
    p = -0.000200214257f;
    p = fmaf(p, w, 0.000100950558f);
    p = fmaf(p, w, 0.00134934322f);
    p = fmaf(p, w, -0.00367342844f);
    p = fmaf(p, w, 0.00573950773f);
    p = fmaf(p, w, -0.0076224613f);
    p = fmaf(p, w, 0.00943887047f);
    p = fmaf(p, w, 1.00167406f);
    p = fmaf(p, w, 2.83297682f);
  }
  return p*x;
}

// 2-plane bf16 split (truncation): x ~= h+m with rel error <= 2^-16
__device__ __forceinline__ void split2(float x, unsigned short &h, unsigned short &m){
  uint32_t xb = __float_as_uint(x);
  h = (unsigned short)(xb >> 16);
  float r = x - __uint_as_float(xb & 0xFFFF0000u);
  m = (unsigned short)(__float_as_uint(r) >> 16);
}

#define MFMA(a,b,c) __builtin_amdgcn_mfma_f32_32x32x16_bf16((a),(b),(c),0,0,0)

// LDS A-planes: 2 planes x 64 rows x 120 bf16, stride 120 (240B rows, 16B-aligned)
#define AROW 120
#define APLANE (64*AROW)

__global__ __launch_bounds__(256, 4) void cem_kernel(
    const float* __restrict__ states, const float* __restrict__ W1,
    const float* __restrict__ b1,     const float* __restrict__ W2,
    const float* __restrict__ b2,     const float* __restrict__ W3,
    const float* __restrict__ b3,     float* __restrict__ out)
{
  __shared__ __align__(16) unsigned short sApl[2*APLANE]; // 30720 B
  __shared__ float qbuf[4][64];
  __shared__ float sSW[HID], sW13[HID];
  __shared__ float sEps[64];
  __shared__ uint32_t sKeys[198];
  __shared__ float sB3;

  const int tid  = threadIdx.x;
  const int b    = blockIdx.x;
  const int wv   = tid >> 6;
  const int lane = tid & 63;
  const int half = lane >> 5;
  const int col  = lane & 31;
  const int n    = wv*32 + col;    // output-neuron column for layer 2

  const float s0 = states[2*b], s1 = states[2*b+1];

  // zero-init A planes (pads must stay zero)
  for (int f = tid; f < APLANE; f += 256) ((unsigned int*)sApl)[f] = 0u;

  if (tid < HID){
    float w0 = W1[tid], w1 = W1[HID+tid];
    sSW[tid]  = fmaf(s0, w0, fmaf(s1, w1, b1[tid]));
    sW13[tid] = W1[2*HID+tid];
  }
  if (tid == 0) sB3 = b3[0];

  // per-lane epilogue constants
  const float bn2 = (n < HID) ? b2[n] : 0.0f;
  const float wn3 = (n < HID) ? W3[n] : 0.0f;

  // one-time: static W2 B-fragments in registers (2-plane bf16 split)
  bf16x8 Bfh[7], Bfm[7];
#pragma unroll
  for (int ks = 0; ks < 7; ++ks){
    FragU fh, fm;
#pragma unroll
    for (int i = 0; i < 8; ++i){
      int k = ks*16 + half*8 + i;
      float w = (k < HID && n < HID) ? W2[k*HID + n] : 0.0f;
      split2(w, fh.s[i], fm.s[i]);
    }
    Bfh[ks] = fh.v; Bfm[ks] = fm.v;
  }

  // key schedule: key(42) = (0,42); split -> k0=(A0,B0), kloop=(A1,B1)
  if (tid < 99){
    uint32_t A0,A1,B0,B1;
    tf2x32(0u,42u,0u,2u,A0,A1);
    tf2x32(0u,42u,1u,3u,B0,B1);
    uint32_t o0,o1;
    tf2x32(A1,B1,(uint32_t)tid,(uint32_t)(99+tid),o0,o1);
    sKeys[tid]    = o0;
    sKeys[99+tid] = o1;
    if (tid < MCAND){
      // iteration-0 "eps" = uniform angles (mu=0, std=1 makes a_c = eps_c)
      uint32_t gidx = (uint32_t)b*MCAND + (uint32_t)tid;
      uint32_t r0,r1,bits;
      if (gidx < 102400u){ tf2x32(A0,B0,gidx,gidx+102400u,r0,r1); bits = r0; }
      else               { tf2x32(A0,B0,gidx-102400u,gidx,r0,r1); bits = r1; }
      sEps[tid] = __uint_as_float((bits>>9) | 0x3f800000u) - 1.0f;
    }
  }
  __syncthreads();

  const float MINV = -0x1.fffffep-1f;   // nextafter(-1,0)
  const float SQRT2 = 0x1.6a09e6p+0f;   // fp32 sqrt(2)

  float mu = 0.0f, stdv = 1.0f;         // per-wave redundant CEM state

#pragma unroll 1
  for (int t = 0; t < 99; ++t){
    // ---- phase 1: a_c = mu + std*eps_c; h1 = relu(sSW + a_c*sW13); split2 to LDS ----
    for (int f = tid; f < MCAND*(HID/2); f += 256){
      int c  = f / (HID/2);
      int k  = (f - c*(HID/2)) * 2;
      float a = fmaf(stdv, sEps[c], mu);
      float2 swp  = *(const float2*)&sSW[k];
      float2 w13p = *(const float2*)&sW13[k];
      float v0 = fmaxf(fmaf(a, w13p.x, swp.x), 0.0f);
      float v1 = fmaxf(fmaf(a, w13p.y, swp.y), 0.0f);
      unsigned short h0,m0,h1_,m1;
      split2(v0, h0, m0);
      split2(v1, h1_, m1);
      int base = c*AROW + k;
      *(unsigned int*)&sApl[base]          = (unsigned int)h0 | ((unsigned int)h1_<<16);
      *(unsigned int*)&sApl[APLANE + base] = (unsigned int)m0 | ((unsigned int)m1 <<16);
    }
    __syncthreads();   // B1

    // ---- phase 2: next-iter eps (overlapped) + MFMA GEMM + q-partials ----
    if (t < 98 && lane < 13){
      int c = wv*13 + lane;
      if (c < MCAND){
        uint32_t kk0 = sKeys[2*t], kk1 = sKeys[2*t+1];
        uint32_t gidx = (uint32_t)b*MCAND + (uint32_t)c;
        uint32_t r0,r1,bits;
        if (gidx < 102400u){ tf2x32(kk0,kk1,gidx,gidx+102400u,r0,r1); bits = r0; }
        else               { tf2x32(kk0,kk1,gidx-102400u,gidx,r0,r1); bits = r1; }
        float fl = __uint_as_float((bits>>9) | 0x3f800000u) - 1.0f;
        float u  = fmaxf(MINV, fl*2.0f + MINV);
        sEps[c]  = SQRT2 * erfinv32(u);
      }
    }

    {
      f32x16 acc0, acc1;
#pragma unroll
      for (int r = 0; r < 16; ++r){ acc0[r] = 0.0f; acc1[r] = 0.0f; }

#pragma unroll
      for (int ks = 0; ks < 7; ++ks){
        const int kb = ks*16 + half*8;
        const int r0 = col*AROW + kb;
        const int r1 = (32+col)*AROW + kb;
        bf16x8 a0h = *(const bf16x8*)&sApl[r0];
        bf16x8 a1h = *(const bf16x8*)&sApl[r1];
        bf16x8 a0m = *(const bf16x8*)&sApl[APLANE + r0];
        bf16x8 a1m = *(const bf16x8*)&sApl[APLANE + r1];
        acc0 = MFMA(a0h, Bfh[ks], acc0);
        acc1 = MFMA(a1h, Bfh[ks], acc1);
        acc0 = MFMA(a0h, Bfm[ks], acc0);
        acc1 = MFMA(a1h, Bfm[ks], acc1);
        acc0 = MFMA(a0m, Bfh[ks], acc0);
        acc1 = MFMA(a1m, Bfh[ks], acc1);
        acc0 = MFMA(a0m, Bfm[ks], acc0);
        acc1 = MFMA(a1m, Bfm[ks], acc1);
      }

      // epilogue: h2 = relu(acc+b2[n]); qpart = h2*W3[n]; reduce over 32 cols
#pragma unroll
      for (int mt = 0; mt < 2; ++mt){
        float qp[16];
#pragma unroll
        for (int r = 0; r < 16; ++r){
          float av = mt ? acc1[r] : acc0[r];
          qp[r] = fmaxf(av + bn2, 0.0f) * wn3;
        }
#pragma unroll
        for (int off = 1; off <= 16; off <<= 1){
#pragma unroll
          for (int r = 0; r < 16; ++r) qp[r] += __shfl_xor(qp[r], off, 64);
        }
        if (col == 0){
#pragma unroll
          for (int r = 0; r < 16; ++r){
            int row = (r&3) + 8*(r>>2) + 4*half + mt*32;
            qbuf[wv][row] = qp[r];
          }
        }
      }
    }
    __syncthreads();   // B2

    // ---- phase 3 (redundant on all 4 waves): q, top-32 stats -> mu, std regs ----
    {
      float q = -INFINITY;
      if (lane < MCAND)
        q = qbuf[0][lane] + qbuf[1][lane] + qbuf[2][lane] + qbuf[3][lane] + sB3;
      // stable rank (permutation -> exactly 32 elites; ties value-identical)
      int rank = 0;
      for (int s = 0; s < MCAND; ++s){
        float qs = __shfl(q, s, 64);
        if (qs > q || (qs == q && s < lane)) rank++;
      }
      bool elite = (lane < MCAND) && (rank < NTOP);
      float sv = elite ? q : 0.0f;
#pragma unroll
      for (int off = 32; off >= 1; off >>= 1) sv += __shfl_xor(sv, off, 64);
      float mun = sv / 32.0f;
      float dv = elite ? (q - mun) : 0.0f;
      float s2 = dv*dv;
#pragma unroll
      for (int off = 32; off >= 1; off >>= 1) s2 += __shfl_xor(s2, off, 64);
      stdv = sqrtf(s2 / 31.0f);
      mu = mun;
      if (t == 98 && tid == 0) out[b] = mu * 6.2831854820251465f;  // fp32(2*pi)
    }
    // no barrier: phase1(t+1) writes race only vs phase2(t) reads (behind B2);
    // qbuf/sEps next written in phase2(t+1), behind B1(t+1).
  }
}

extern "C" void kernel_launch(void* const* d_in, const int* in_sizes, int n_in,
                              void* d_out, int out_size, void* d_ws, size_t ws_size,
                              hipStream_t stream) {
  const float* states = (const float*)d_in[0];
  const float* W1     = (const float*)d_in[1];
  const float* b1     = (const float*)d_in[2];
  const float* W2     = (const float*)d_in[3];
  const float* b2     = (const float*)d_in[4];
  const float* W3     = (const float*)d_in[5];
  const float* b3     = (const float*)d_in[6];
  float* out = (float*)d_out;
  hipLaunchKernelGGL(cem_kernel, dim3(BATCH), dim3(256), 0, stream,
                     states, W1, b1, W2, b2, W3, b3, out);
}

// Round 4
// 3218.281 us; speedup vs baseline: 3.0799x; 1.7937x over previous
//
#include <hip/hip_runtime.h>
#include <math.h>
#include <stdint.h>

#define BATCH 4096
#define MCAND 50
#define NTOP 32
#define HID 100

typedef __attribute__((ext_vector_type(8))) short bf16x8;
typedef __attribute__((ext_vector_type(16))) float f32x16;

union FragU { bf16x8 v; unsigned short s[8]; };

__device__ __forceinline__ uint32_t rotl32(uint32_t v, int d){ return (v<<d)|(v>>(32-d)); }

// JAX threefry2x32 core (20 rounds, 5 key injections)
__device__ __forceinline__ void tf2x32(uint32_t k0, uint32_t k1, uint32_t x0, uint32_t x1,
                                       uint32_t &o0, uint32_t &o1){
  uint32_t k2 = k0 ^ k1 ^ 0x1BD11BDAu;
  x0 += k0; x1 += k1;
#define RND(r) { x0 += x1; x1 = rotl32(x1,(r)); x1 ^= x0; }
  RND(13) RND(15) RND(26) RND(6)
  x0 += k1; x1 += k2 + 1u;
  RND(17) RND(29) RND(16) RND(24)
  x0 += k2; x1 += k0 + 2u;
  RND(13) RND(15) RND(26) RND(6)
  x0 += k0; x1 += k1 + 3u;
  RND(17) RND(29) RND(16) RND(24)
  x0 += k1; x1 += k2 + 4u;
  RND(13) RND(15) RND(26) RND(6)
  x0 += k2; x1 += k0 + 5u;
#undef RND
  o0 = x0; o1 = x1;
}

// XLA ErfInv32 (Giles). w = -log1p(-x*x)
__device__ __forceinline__ float erfinv32(float x){
  float w = -log1pf(-x*x);
  float p;
  if (w < 5.0f){
    w = w - 2.5f;
    p = 2.81022636e-08f;
    p = fmaf(p, w, 3.43273939e-07f);
    p = fmaf(p, w, -3.5233877e-06f);
    p = fmaf(p, w, -4.39150654e-06f);
    p = fmaf(p, w, 0.00021858087f);
    p = fmaf(p, w, -0.00125372503f);
    p = fmaf(p, w, -0.00417768164f);
    p = fmaf(p, w, 0.246640727f);
    p = fmaf(p, w, 1.50140941f);
  } else {
    w = sqrtf(w) - 3.0f;
    p = -0.000200214257f;
    p = fmaf(p, w, 0.000100950558f);
    p = fmaf(p, w, 0.00134934322f);
    p = fmaf(p, w, -0.00367342844f);
    p = fmaf(p, w, 0.00573950773f);
    p = fmaf(p, w, -0.0076224613f);
    p = fmaf(p, w, 0.00943887047f);
    p = fmaf(p, w, 1.00167406f);
    p = fmaf(p, w, 2.83297682f);
  }
  return p*x;
}

// 2-plane bf16 split (truncation): x ~= h+m with rel error <= 2^-16
__device__ __forceinline__ void split2(float x, unsigned short &h, unsigned short &m){
  uint32_t xb = __float_as_uint(x);
  h = (unsigned short)(xb >> 16);
  float r = x - __uint_as_float(xb & 0xFFFF0000u);
  m = (unsigned short)(__float_as_uint(r) >> 16);
}

#define MFMA(a,b,c) __builtin_amdgcn_mfma_f32_32x32x16_bf16((a),(b),(c),0,0,0)

// LDS A-planes: 2 planes x 64 rows x 104 bf16 (208B rows; word-step 52 == 20 mod 32,
// gcd(20,32)=4 -> 8 consecutive cols tile all 32 banks for b128 reads)
#define AROW 104
#define APLANE (64*AROW)

__global__ __launch_bounds__(256, 5) void cem_kernel(
    const float* __restrict__ states, const float* __restrict__ W1,
    const float* __restrict__ b1,     const float* __restrict__ W2,
    const float* __restrict__ b2,     const float* __restrict__ W3,
    const float* __restrict__ b3,     float* __restrict__ out)
{
  __shared__ __align__(16) unsigned short sApl[2*APLANE]; // 26624 B
  __shared__ float qbuf[4][64];
  __shared__ float sSW[HID], sW13[HID];
  __shared__ float sEps[64];
  __shared__ uint32_t sKeys[198];
  __shared__ float sB3;

  const int tid  = threadIdx.x;
  const int b    = blockIdx.x;
  const int wv   = tid >> 6;
  const int lane = tid & 63;
  const int half = lane >> 5;
  const int col  = lane & 31;
  const int n    = wv*32 + col;    // output-neuron column for layer 2

  const float s0 = states[2*b], s1 = states[2*b+1];

  // zero-init A planes (pads must stay zero)
  for (int f = tid; f < APLANE; f += 256) ((unsigned int*)sApl)[f] = 0u;

  if (tid < HID){
    float w0 = W1[tid], w1 = W1[HID+tid];
    sSW[tid]  = fmaf(s0, w0, fmaf(s1, w1, b1[tid]));
    sW13[tid] = W1[2*HID+tid];
  }
  if (tid == 0) sB3 = b3[0];

  // per-lane epilogue constants
  const float bn2 = (n < HID) ? b2[n] : 0.0f;
  const float wn3 = (n < HID) ? W3[n] : 0.0f;

  // one-time: static W2 B-fragments in registers (2-plane bf16 split)
  bf16x8 Bfh[7], Bfm[7];
#pragma unroll
  for (int ks = 0; ks < 7; ++ks){
    FragU fh, fm;
#pragma unroll
    for (int i = 0; i < 8; ++i){
      int k = ks*16 + half*8 + i;
      float w = (k < HID && n < HID) ? W2[k*HID + n] : 0.0f;
      split2(w, fh.s[i], fm.s[i]);
    }
    Bfh[ks] = fh.v; Bfm[ks] = fm.v;
  }

  // key schedule: key(42) = (0,42); split -> k0=(A0,B0), kloop=(A1,B1)
  if (tid < 99){
    uint32_t A0,A1,B0,B1;
    tf2x32(0u,42u,0u,2u,A0,A1);
    tf2x32(0u,42u,1u,3u,B0,B1);
    uint32_t o0,o1;
    tf2x32(A1,B1,(uint32_t)tid,(uint32_t)(99+tid),o0,o1);
    sKeys[tid]    = o0;
    sKeys[99+tid] = o1;
    if (tid < MCAND){
      // iteration-0 "eps" = uniform angles (mu=0, std=1 makes a_c = eps_c)
      uint32_t gidx = (uint32_t)b*MCAND + (uint32_t)tid;
      uint32_t r0,r1,bits;
      if (gidx < 102400u){ tf2x32(A0,B0,gidx,gidx+102400u,r0,r1); bits = r0; }
      else               { tf2x32(A0,B0,gidx-102400u,gidx,r0,r1); bits = r1; }
      sEps[tid] = __uint_as_float((bits>>9) | 0x3f800000u) - 1.0f;
    }
  }
  __syncthreads();

  const float MINV = -0x1.fffffep-1f;   // nextafter(-1,0)
  const float SQRT2 = 0x1.6a09e6p+0f;   // fp32 sqrt(2)

  float mu = 0.0f, stdv = 1.0f;         // per-wave redundant CEM state

#pragma unroll 1
  for (int t = 0; t < 99; ++t){
    // ---- phase 1: a_c = mu + std*eps_c; h1 = relu(sSW + a_c*sW13); split2 to LDS ----
    for (int f = tid; f < MCAND*(HID/2); f += 256){
      int c  = f / (HID/2);
      int k  = (f - c*(HID/2)) * 2;
      float a = fmaf(stdv, sEps[c], mu);
      float2 swp  = *(const float2*)&sSW[k];
      float2 w13p = *(const float2*)&sW13[k];
      float v0 = fmaxf(fmaf(a, w13p.x, swp.x), 0.0f);
      float v1 = fmaxf(fmaf(a, w13p.y, swp.y), 0.0f);
      unsigned short h0,m0,h1_,m1;
      split2(v0, h0, m0);
      split2(v1, h1_, m1);
      int base = c*AROW + k;
      *(unsigned int*)&sApl[base]          = (unsigned int)h0 | ((unsigned int)h1_<<16);
      *(unsigned int*)&sApl[APLANE + base] = (unsigned int)m0 | ((unsigned int)m1 <<16);
    }
    __syncthreads();   // B1

    // ---- phase 2: next-iter eps (wave 3 only, overlapped) + MFMA GEMM ----
    if (wv == 3 && t < 98 && lane < MCAND){
      uint32_t kk0 = sKeys[2*t], kk1 = sKeys[2*t+1];
      uint32_t gidx = (uint32_t)b*MCAND + (uint32_t)lane;
      uint32_t r0,r1,bits;
      if (gidx < 102400u){ tf2x32(kk0,kk1,gidx,gidx+102400u,r0,r1); bits = r0; }
      else               { tf2x32(kk0,kk1,gidx-102400u,gidx,r0,r1); bits = r1; }
      float fl = __uint_as_float((bits>>9) | 0x3f800000u) - 1.0f;
      float u  = fmaxf(MINV, fl*2.0f + MINV);
      sEps[lane] = SQRT2 * erfinv32(u);
    }

    {
      f32x16 acc0, acc1;
#pragma unroll
      for (int r = 0; r < 16; ++r){ acc0[r] = 0.0f; acc1[r] = 0.0f; }

#pragma unroll
      for (int ks = 0; ks < 7; ++ks){
        const int kb = ks*16 + half*8;
        const int r0 = col*AROW + kb;
        const int r1 = (32+col)*AROW + kb;
        bf16x8 a0h = *(const bf16x8*)&sApl[r0];
        bf16x8 a1h = *(const bf16x8*)&sApl[r1];
        bf16x8 a0m = *(const bf16x8*)&sApl[APLANE + r0];
        bf16x8 a1m = *(const bf16x8*)&sApl[APLANE + r1];
        acc0 = MFMA(a0h, Bfh[ks], acc0);
        acc1 = MFMA(a1h, Bfh[ks], acc1);
        acc0 = MFMA(a0h, Bfm[ks], acc0);
        acc1 = MFMA(a1h, Bfm[ks], acc1);
        acc0 = MFMA(a0m, Bfh[ks], acc0);
        acc1 = MFMA(a1m, Bfh[ks], acc1);
        acc0 = MFMA(a0m, Bfm[ks], acc0);
        acc1 = MFMA(a1m, Bfm[ks], acc1);
      }

      // epilogue: h2 = relu(acc+b2[n]); qpart = h2*W3[n]
      float v0[16], v1[16];
#pragma unroll
      for (int r = 0; r < 16; ++r){
        v0[r] = fmaxf(acc0[r] + bn2, 0.0f) * wn3;
        v1[r] = fmaxf(acc1[r] + bn2, 0.0f) * wn3;
      }
      // concentrated reduction over 32 columns: reg halving each step;
      // after 4 steps lane holds reg r=col&15 summed over its 16-col group,
      // final xor-16 completes the 32-col sum.
#pragma unroll
      for (int step = 0; step < 4; ++step){
        const int off = 1 << step;
        const bool hi = (col & off) != 0;
        const int nn = 16 >> step;
#pragma unroll
        for (int i = 0; i < nn/2; ++i){
          float a0 = v0[2*i]   + __shfl_xor(v0[2*i],   off, 64);
          float b0 = v0[2*i+1] + __shfl_xor(v0[2*i+1], off, 64);
          v0[i] = hi ? b0 : a0;
          float a1 = v1[2*i]   + __shfl_xor(v1[2*i],   off, 64);
          float b1_ = v1[2*i+1] + __shfl_xor(v1[2*i+1], off, 64);
          v1[i] = hi ? b1_ : a1;
        }
      }
      float red0 = v0[0] + __shfl_xor(v0[0], 16, 64);
      float red1 = v1[0] + __shfl_xor(v1[0], 16, 64);
      const int c15 = col & 15;
      const int row = (c15 & 3) + 8*(c15 >> 2) + 4*half;
      if (col < 16) qbuf[wv][row]      = red0;
      else          qbuf[wv][row + 32] = red1;
    }
    __syncthreads();   // B2

    // ---- phase 3 (redundant on all 4 waves): bitonic top-32 stats ----
    {
      float q = -INFINITY;
      if (lane < MCAND)
        q = qbuf[0][lane] + qbuf[1][lane] + qbuf[2][lane] + qbuf[3][lane] + sB3;
      // 64-lane bitonic sort, descending (ties have identical values ->
      // unstable order doesn't change the top-32 multiset)
      float v = q;
#pragma unroll
      for (int k = 2; k <= 64; k <<= 1){
#pragma unroll
        for (int j = k >> 1; j >= 1; j >>= 1){
          float pv = __shfl_xor(v, j, 64);
          bool lower = (lane & j) == 0;
          bool asc   = (lane & k) != 0;
          float mn = fminf(v, pv), mx = fmaxf(v, pv);
          v = (lower == asc) ? mn : mx;
        }
      }
      float sv = (lane < NTOP) ? v : 0.0f;
#pragma unroll
      for (int off = 32; off >= 1; off >>= 1) sv += __shfl_xor(sv, off, 64);
      float mun = sv / 32.0f;
      float dv = (lane < NTOP) ? (v - mun) : 0.0f;
      float s2 = dv*dv;
#pragma unroll
      for (int off = 32; off >= 1; off >>= 1) s2 += __shfl_xor(s2, off, 64);
      stdv = sqrtf(s2 / 31.0f);
      mu = mun;
      if (t == 98 && tid == 0) out[b] = mu * 6.2831854820251465f;  // fp32(2*pi)
    }
    // no barrier: phase1(t+1) writes sApl race only vs phase2(t) reads (behind B2);
    // qbuf/sEps next written in phase2(t+1), behind B1(t+1).
  }
}

extern "C" void kernel_launch(void* const* d_in, const int* in_sizes, int n_in,
                              void* d_out, int out_size, void* d_ws, size_t ws_size,
                              hipStream_t stream) {
  const float* states = (const float*)d_in[0];
  const float* W1     = (const float*)d_in[1];
  const float* b1     = (const float*)d_in[2];
  const float* W2     = (const float*)d_in[3];
  const float* b2     = (const float*)d_in[4];
  const float* W3     = (const float*)d_in[5];
  const float* b3     = (const float*)d_in[6];
  float* out = (float*)d_out;
  hipLaunchKernelGGL(cem_kernel, dim3(BATCH), dim3(256), 0, stream,
                     states, W1, b1, W2, b2, W3, b3, out);
}

// Round 5
// 2901.897 us; speedup vs baseline: 3.4157x; 1.1090x over previous
//
#include <hip/hip_runtime.h>
#include <math.h>
#include <stdint.h>

#define BATCH 4096
#define MCAND 50
#define NTOP 32
#define HID 100

typedef __attribute__((ext_vector_type(8))) short bf16x8;
typedef __attribute__((ext_vector_type(16))) float f32x16;

union FragU { bf16x8 v; unsigned short s[8]; };

__device__ __forceinline__ uint32_t rotl32(uint32_t v, int d){ return (v<<d)|(v>>(32-d)); }

// JAX threefry2x32 core (20 rounds, 5 key injections)
__device__ __forceinline__ void tf2x32(uint32_t k0, uint32_t k1, uint32_t x0, uint32_t x1,
                                       uint32_t &o0, uint32_t &o1){
  uint32_t k2 = k0 ^ k1 ^ 0x1BD11BDAu;
  x0 += k0; x1 += k1;
#define RND(r) { x0 += x1; x1 = rotl32(x1,(r)); x1 ^= x0; }
  RND(13) RND(15) RND(26) RND(6)
  x0 += k1; x1 += k2 + 1u;
  RND(17) RND(29) RND(16) RND(24)
  x0 += k2; x1 += k0 + 2u;
  RND(13) RND(15) RND(26) RND(6)
  x0 += k0; x1 += k1 + 3u;
  RND(17) RND(29) RND(16) RND(24)
  x0 += k1; x1 += k2 + 4u;
  RND(13) RND(15) RND(26) RND(6)
  x0 += k2; x1 += k0 + 5u;
#undef RND
  o0 = x0; o1 = x1;
}

// XLA ErfInv32 (Giles). w = -log1p(-x*x)
__device__ __forceinline__ float erfinv32(float x){
  float w = -log1pf(-x*x);
  float p;
  if (w < 5.0f){
    w = w - 2.5f;
    p = 2.81022636e-08f;
    p = fmaf(p, w, 3.43273939e-07f);
    p = fmaf(p, w, -3.5233877e-06f);
    p = fmaf(p, w, -4.39150654e-06f);
    p = fmaf(p, w, 0.00021858087f);
    p = fmaf(p, w, -0.00125372503f);
    p = fmaf(p, w, -0.00417768164f);
    p = fmaf(p, w, 0.246640727f);
    p = fmaf(p, w, 1.50140941f);
  } else {
    w = sqrtf(w) - 3.0f;
    p = -0.000200214257f;
    p = fmaf(p, w, 0.000100950558f);
    p = fmaf(p, w, 0.00134934322f);
    p = fmaf(p, w, -0.00367342844f);
    p = fmaf(p, w, 0.00573950773f);
    p = fmaf(p, w, -0.0076224613f);
    p = fmaf(p, w, 0.00943887047f);
    p = fmaf(p, w, 1.00167406f);
    p = fmaf(p, w, 2.83297682f);
  }
  return p*x;
}

// 2-plane bf16 split (truncation): x ~= h+m with rel error <= 2^-16
__device__ __forceinline__ void split2(float x, unsigned short &h, unsigned short &m){
  uint32_t xb = __float_as_uint(x);
  h = (unsigned short)(xb >> 16);
  float r = x - __uint_as_float(xb & 0xFFFF0000u);
  m = (unsigned short)(__float_as_uint(r) >> 16);
}

#define MFMA(a,b,c) __builtin_amdgcn_mfma_f32_32x32x16_bf16((a),(b),(c),0,0,0)

// LDS A-planes: 2 planes x 64 rows x 104 bf16 (208B rows; word-step 52 == 20 mod 32)
#define AROW 104
#define APLANE (64*AROW)

__global__ __launch_bounds__(256, 4) void cem_kernel(
    const float* __restrict__ states, const float* __restrict__ W1,
    const float* __restrict__ b1,     const float* __restrict__ W2,
    const float* __restrict__ b2,     const float* __restrict__ W3,
    const float* __restrict__ b3,     float* __restrict__ out)
{
  __shared__ __align__(16) unsigned short sApl[2*APLANE]; // 26624 B
  __shared__ float qbuf[4][64];
  __shared__ float sSW[HID], sW13[HID];
  __shared__ float sEps[64];
  __shared__ uint32_t sKeys[198];
  __shared__ float sB3;

  const int tid  = threadIdx.x;
  const int b    = blockIdx.x;
  const int wv   = tid >> 6;
  const int lane = tid & 63;
  const int half = lane >> 5;
  const int col  = lane & 31;
  const int n    = wv*32 + col;    // output-neuron column for layer 2

  const float s0 = states[2*b], s1 = states[2*b+1];

  // zero-init A planes (pads must stay zero)
  for (int f = tid; f < APLANE; f += 256) ((unsigned int*)sApl)[f] = 0u;

  if (tid < HID){
    float w0 = W1[tid], w1 = W1[HID+tid];
    sSW[tid]  = fmaf(s0, w0, fmaf(s1, w1, b1[tid]));
    sW13[tid] = W1[2*HID+tid];
  }
  if (tid == 0) sB3 = b3[0];

  // per-lane epilogue constants
  const float bn2 = (n < HID) ? b2[n] : 0.0f;
  const float wn3 = (n < HID) ? W3[n] : 0.0f;

  // one-time: static W2 B-fragments in registers (2-plane bf16 split)
  bf16x8 Bfh[7], Bfm[7];
#pragma unroll
  for (int ks = 0; ks < 7; ++ks){
    FragU fh, fm;
#pragma unroll
    for (int i = 0; i < 8; ++i){
      int k = ks*16 + half*8 + i;
      float w = (k < HID && n < HID) ? W2[k*HID + n] : 0.0f;
      split2(w, fh.s[i], fm.s[i]);
    }
    Bfh[ks] = fh.v; Bfm[ks] = fm.v;
  }

  // key schedule: key(42) = (0,42); split -> k0=(A0,B0), kloop=(A1,B1)
  if (tid < 99){
    uint32_t A0,A1,B0,B1;
    tf2x32(0u,42u,0u,2u,A0,A1);
    tf2x32(0u,42u,1u,3u,B0,B1);
    uint32_t o0,o1;
    tf2x32(A1,B1,(uint32_t)tid,(uint32_t)(99+tid),o0,o1);
    sKeys[tid]    = o0;
    sKeys[99+tid] = o1;
    if (tid < MCAND){
      // iteration-0 "eps" = uniform angles (mu=0, std=1 makes a_c = eps_c)
      uint32_t gidx = (uint32_t)b*MCAND + (uint32_t)tid;
      uint32_t r0,r1,bits;
      if (gidx < 102400u){ tf2x32(A0,B0,gidx,gidx+102400u,r0,r1); bits = r0; }
      else               { tf2x32(A0,B0,gidx-102400u,gidx,r0,r1); bits = r1; }
      sEps[tid] = __uint_as_float((bits>>9) | 0x3f800000u) - 1.0f;
    }
  }
  __syncthreads();

  const float MINV = -0x1.fffffep-1f;   // nextafter(-1,0)
  const float SQRT2 = 0x1.6a09e6p+0f;   // fp32 sqrt(2)

  float mu = 0.0f, stdv = 1.0f;         // per-wave redundant CEM state

#pragma unroll 1
  for (int t = 0; t < 99; ++t){
    // ---- phase 1: a_c = mu + std*eps_c; h1 = relu(sSW + a_c*sW13); split2 to LDS ----
    for (int f = tid; f < MCAND*(HID/2); f += 256){
      int c  = f / (HID/2);
      int k  = (f - c*(HID/2)) * 2;
      float a = fmaf(stdv, sEps[c], mu);
      float2 swp  = *(const float2*)&sSW[k];
      float2 w13p = *(const float2*)&sW13[k];
      float v0 = fmaxf(fmaf(a, w13p.x, swp.x), 0.0f);
      float v1 = fmaxf(fmaf(a, w13p.y, swp.y), 0.0f);
      unsigned short h0,m0,h1_,m1;
      split2(v0, h0, m0);
      split2(v1, h1_, m1);
      int base = c*AROW + k;
      *(unsigned int*)&sApl[base]          = (unsigned int)h0 | ((unsigned int)h1_<<16);
      *(unsigned int*)&sApl[APLANE + base] = (unsigned int)m0 | ((unsigned int)m1 <<16);
    }
    __syncthreads();   // B1

    // ---- phase 2: next-iter eps (wave 3 only, overlapped) + MFMA GEMM ----
    if (wv == 3 && t < 98 && lane < MCAND){
      uint32_t kk0 = sKeys[2*t], kk1 = sKeys[2*t+1];
      uint32_t gidx = (uint32_t)b*MCAND + (uint32_t)lane;
      uint32_t r0,r1,bits;
      if (gidx < 102400u){ tf2x32(kk0,kk1,gidx,gidx+102400u,r0,r1); bits = r0; }
      else               { tf2x32(kk0,kk1,gidx-102400u,gidx,r0,r1); bits = r1; }
      float fl = __uint_as_float((bits>>9) | 0x3f800000u) - 1.0f;
      float u  = fmaxf(MINV, fl*2.0f + MINV);
      sEps[lane] = SQRT2 * erfinv32(u);
    }

    {
      f32x16 acc0, acc1;
#pragma unroll
      for (int r = 0; r < 16; ++r){ acc0[r] = 0.0f; acc1[r] = 0.0f; }

#pragma unroll
      for (int ks = 0; ks < 7; ++ks){
        const int kb = ks*16 + half*8;
        const int r0 = col*AROW + kb;
        const int r1 = (32+col)*AROW + kb;
        bf16x8 a0h = *(const bf16x8*)&sApl[r0];
        bf16x8 a1h = *(const bf16x8*)&sApl[r1];
        bf16x8 a0m = *(const bf16x8*)&sApl[APLANE + r0];
        bf16x8 a1m = *(const bf16x8*)&sApl[APLANE + r1];
        acc0 = MFMA(a0h, Bfh[ks], acc0);
        acc1 = MFMA(a1h, Bfh[ks], acc1);
        acc0 = MFMA(a0h, Bfm[ks], acc0);
        acc1 = MFMA(a1h, Bfm[ks], acc1);
        acc0 = MFMA(a0m, Bfh[ks], acc0);
        acc1 = MFMA(a1m, Bfh[ks], acc1);
        acc0 = MFMA(a0m, Bfm[ks], acc0);
        acc1 = MFMA(a1m, Bfm[ks], acc1);
      }

      // epilogue IN-PLACE on acc (acc is dead after this; re-zeroed next iter):
      // h2 = relu(acc+b2[n]); qpart = h2*W3[n]
#pragma unroll
      for (int r = 0; r < 16; ++r){
        acc0[r] = fmaxf(acc0[r] + bn2, 0.0f) * wn3;
        acc1[r] = fmaxf(acc1[r] + bn2, 0.0f) * wn3;
      }
      // concentrated reduction over 32 columns: reg halving each step;
      // after 4 steps lane holds reg r=col&15 summed over its 16-col group,
      // final xor-16 completes the 32-col sum.
#pragma unroll
      for (int step = 0; step < 4; ++step){
        const int off = 1 << step;
        const bool hi = (col & off) != 0;
        const int nn = 16 >> step;
#pragma unroll
        for (int i = 0; i < nn/2; ++i){
          float a0 = acc0[2*i]   + __shfl_xor(acc0[2*i],   off, 64);
          float b0 = acc0[2*i+1] + __shfl_xor(acc0[2*i+1], off, 64);
          acc0[i] = hi ? b0 : a0;
          float a1 = acc1[2*i]   + __shfl_xor(acc1[2*i],   off, 64);
          float b1_ = acc1[2*i+1] + __shfl_xor(acc1[2*i+1], off, 64);
          acc1[i] = hi ? b1_ : a1;
        }
      }
      float red0 = acc0[0] + __shfl_xor(acc0[0], 16, 64);
      float red1 = acc1[0] + __shfl_xor(acc1[0], 16, 64);
      const int c15 = col & 15;
      const int row = (c15 & 3) + 8*(c15 >> 2) + 4*half;
      if (col < 16) qbuf[wv][row]      = red0;
      else          qbuf[wv][row + 32] = red1;
    }
    __syncthreads();   // B2

    // ---- phase 3 (redundant on all 4 waves): bitonic top-32 stats ----
    {
      float q = -INFINITY;
      if (lane < MCAND)
        q = qbuf[0][lane] + qbuf[1][lane] + qbuf[2][lane] + qbuf[3][lane] + sB3;
      // 64-lane bitonic sort, descending (ties have identical values ->
      // unstable order doesn't change the top-32 multiset)
      float v = q;
#pragma unroll
      for (int k = 2; k <= 64; k <<= 1){
#pragma unroll
        for (int j = k >> 1; j >= 1; j >>= 1){
          float pv = __shfl_xor(v, j, 64);
          bool lower = (lane & j) == 0;
          bool asc   = (lane & k) != 0;
          float mn = fminf(v, pv), mx = fmaxf(v, pv);
          v = (lower == asc) ? mn : mx;
        }
      }
      float sv = (lane < NTOP) ? v : 0.0f;
#pragma unroll
      for (int off = 32; off >= 1; off >>= 1) sv += __shfl_xor(sv, off, 64);
      float mun = sv / 32.0f;
      float dv = (lane < NTOP) ? (v - mun) : 0.0f;
      float s2 = dv*dv;
#pragma unroll
      for (int off = 32; off >= 1; off >>= 1) s2 += __shfl_xor(s2, off, 64);
      stdv = sqrtf(s2 / 31.0f);
      mu = mun;
      if (t == 98 && tid == 0) out[b] = mu * 6.2831854820251465f;  // fp32(2*pi)
    }
    // no barrier: phase1(t+1) writes sApl race only vs phase2(t) reads (behind B2);
    // qbuf/sEps next written in phase2(t+1), behind B1(t+1).
  }
}

extern "C" void kernel_launch(void* const* d_in, const int* in_sizes, int n_in,
                              void* d_out, int out_size, void* d_ws, size_t ws_size,
                              hipStream_t stream) {
  const float* states = (const float*)d_in[0];
  const float* W1     = (const float*)d_in[1];
  const float* b1     = (const float*)d_in[2];
  const float* W2     = (const float*)d_in[3];
  const float* b2     = (const float*)d_in[4];
  const float* W3     = (const float*)d_in[5];
  const float* b3     = (const float*)d_in[6];
  float* out = (float*)d_out;
  hipLaunchKernelGGL(cem_kernel, dim3(BATCH), dim3(256), 0, stream,
                     states, W1, b1, W2, b2, W3, b3, out);
}

// Round 6
// 2555.818 us; speedup vs baseline: 3.8782x; 1.1354x over previous
//
#include <hip/hip_runtime.h>
#include <math.h>
#include <stdint.h>

#define BATCH 4096
#define MCAND 50
#define NTOP 32
#define HID 100

typedef __attribute__((ext_vector_type(8))) short bf16x8;
typedef __attribute__((ext_vector_type(16))) float f32x16;

union FragU { bf16x8 v; unsigned short s[8]; };

__device__ __forceinline__ uint32_t rotl32(uint32_t v, int d){ return (v<<d)|(v>>(32-d)); }

// JAX threefry2x32 core (20 rounds, 5 key injections)
__device__ __forceinline__ void tf2x32(uint32_t k0, uint32_t k1, uint32_t x0, uint32_t x1,
                                       uint32_t &o0, uint32_t &o1){
  uint32_t k2 = k0 ^ k1 ^ 0x1BD11BDAu;
  x0 += k0; x1 += k1;
#define RND(r) { x0 += x1; x1 = rotl32(x1,(r)); x1 ^= x0; }
  RND(13) RND(15) RND(26) RND(6)
  x0 += k1; x1 += k2 + 1u;
  RND(17) RND(29) RND(16) RND(24)
  x0 += k2; x1 += k0 + 2u;
  RND(13) RND(15) RND(26) RND(6)
  x0 += k0; x1 += k1 + 3u;
  RND(17) RND(29) RND(16) RND(24)
  x0 += k1; x1 += k2 + 4u;
  RND(13) RND(15) RND(26) RND(6)
  x0 += k2; x1 += k0 + 5u;
#undef RND
  o0 = x0; o1 = x1;
}

// XLA ErfInv32 (Giles). w = -log1p(-x*x)
__device__ __forceinline__ float erfinv32(float x){
  float w = -log1pf(-x*x);
  float p;
  if (w < 5.0f){
    w = w - 2.5f;
    p = 2.81022636e-08f;
    p = fmaf(p, w, 3.43273939e-07f);
    p = fmaf(p, w, -3.5233877e-06f);
    p = fmaf(p, w, -4.39150654e-06f);
    p = fmaf(p, w, 0.00021858087f);
    p = fmaf(p, w, -0.00125372503f);
    p = fmaf(p, w, -0.00417768164f);
    p = fmaf(p, w, 0.246640727f);
    p = fmaf(p, w, 1.50140941f);
  } else {
    w = sqrtf(w) - 3.0f;
    p = -0.000200214257f;
    p = fmaf(p, w, 0.000100950558f);
    p = fmaf(p, w, 0.00134934322f);
    p = fmaf(p, w, -0.00367342844f);
    p = fmaf(p, w, 0.00573950773f);
    p = fmaf(p, w, -0.0076224613f);
    p = fmaf(p, w, 0.00943887047f);
    p = fmaf(p, w, 1.00167406f);
    p = fmaf(p, w, 2.83297682f);
  }
  return p*x;
}

// 2-plane bf16 split (truncation): x ~= h+m with rel error <= 2^-16
__device__ __forceinline__ void split2(float x, unsigned short &h, unsigned short &m){
  uint32_t xb = __float_as_uint(x);
  h = (unsigned short)(xb >> 16);
  float r = x - __uint_as_float(xb & 0xFFFF0000u);
  m = (unsigned short)(__float_as_uint(r) >> 16);
}

#define MFMA(a,b,c) __builtin_amdgcn_mfma_f32_32x32x16_bf16((a),(b),(c),0,0,0)

// LDS A-planes: 2 planes x 64 rows x 104 bf16 (208B rows; word-step 52 == 20 mod 32)
#define AROW 104
#define APLANE (64*AROW)

__global__ __launch_bounds__(256, 4) void cem_kernel(
    const float* __restrict__ states, const float* __restrict__ W1,
    const float* __restrict__ b1,     const float* __restrict__ W2,
    const float* __restrict__ b2,     const float* __restrict__ W3,
    const float* __restrict__ b3,     float* __restrict__ out)
{
  __shared__ __align__(16) unsigned short sApl[2*APLANE]; // 26624 B
  __shared__ float qbuf[4][64];
  __shared__ __align__(16) float sSW[HID];
  __shared__ __align__(16) float sW13[HID];
  __shared__ float sEps[64];
  __shared__ uint32_t sKeys[198];
  __shared__ float sB3;

  const int tid  = threadIdx.x;
  const int b    = blockIdx.x;
  const int wv   = tid >> 6;
  const int lane = tid & 63;
  const int half = lane >> 5;
  const int col  = lane & 31;
  const int n    = wv*32 + col;    // output-neuron column for layer 2

  const float s0 = states[2*b], s1 = states[2*b+1];

  // zero-init A planes (pads must stay zero)
  for (int f = tid; f < APLANE; f += 256) ((unsigned int*)sApl)[f] = 0u;

  if (tid < HID){
    float w0 = W1[tid], w1 = W1[HID+tid];
    sSW[tid]  = fmaf(s0, w0, fmaf(s1, w1, b1[tid]));
    sW13[tid] = W1[2*HID+tid];
  }
  if (tid == 0) sB3 = b3[0];

  // per-lane epilogue constants
  const float bn2 = (n < HID) ? b2[n] : 0.0f;
  const float wn3 = (n < HID) ? W3[n] : 0.0f;

  // one-time: static W2 B-fragments in registers (2-plane bf16 split)
  bf16x8 Bfh[7], Bfm[7];
#pragma unroll
  for (int ks = 0; ks < 7; ++ks){
    FragU fh, fm;
#pragma unroll
    for (int i = 0; i < 8; ++i){
      int k = ks*16 + half*8 + i;
      float w = (k < HID && n < HID) ? W2[k*HID + n] : 0.0f;
      split2(w, fh.s[i], fm.s[i]);
    }
    Bfh[ks] = fh.v; Bfm[ks] = fm.v;
  }

  // phase-1 fixed ownership: thread -> (candidate c_own, 20-wide k strip)
  const bool p1act = (tid < 250);
  const int  c_own = tid / 5;            // hoisted division (once)
  const int  k0own = (tid - c_own*5) * 20;
  const int  baseown = c_own*AROW + k0own;

  // key schedule: key(42) = (0,42); split -> k0=(A0,B0), kloop=(A1,B1)
  if (tid < 99){
    uint32_t A0,A1,B0,B1;
    tf2x32(0u,42u,0u,2u,A0,A1);
    tf2x32(0u,42u,1u,3u,B0,B1);
    uint32_t o0,o1;
    tf2x32(A1,B1,(uint32_t)tid,(uint32_t)(99+tid),o0,o1);
    sKeys[tid]    = o0;
    sKeys[99+tid] = o1;
    if (tid < MCAND){
      // iteration-0 "eps" = uniform angles (mu=0, std=1 makes a_c = eps_c)
      uint32_t gidx = (uint32_t)b*MCAND + (uint32_t)tid;
      uint32_t r0,r1,bits;
      if (gidx < 102400u){ tf2x32(A0,B0,gidx,gidx+102400u,r0,r1); bits = r0; }
      else               { tf2x32(A0,B0,gidx-102400u,gidx,r0,r1); bits = r1; }
      sEps[tid] = __uint_as_float((bits>>9) | 0x3f800000u) - 1.0f;
    }
  }
  __syncthreads();

  const float MINV = -0x1.fffffep-1f;   // nextafter(-1,0)
  const float SQRT2 = 0x1.6a09e6p+0f;   // fp32 sqrt(2)

  float mu = 0.0f, stdv = 1.0f;         // per-wave redundant CEM state

#pragma unroll 1
  for (int t = 0; t < 99; ++t){
    // ---- phase 1: a_c = mu + std*eps_c; h1 = relu(sSW + a_c*sW13); split2 to LDS ----
    if (p1act){
      const float a = fmaf(stdv, sEps[c_own], mu);
#pragma unroll
      for (int i = 0; i < 5; ++i){
        const int k = k0own + 4*i;
        float4 sw  = *(const float4*)&sSW[k];
        float4 w13 = *(const float4*)&sW13[k];
        float v0 = fmaxf(fmaf(a, w13.x, sw.x), 0.0f);
        float v1 = fmaxf(fmaf(a, w13.y, sw.y), 0.0f);
        float v2 = fmaxf(fmaf(a, w13.z, sw.z), 0.0f);
        float v3 = fmaxf(fmaf(a, w13.w, sw.w), 0.0f);
        uint32_t x0 = __float_as_uint(v0), x1 = __float_as_uint(v1);
        uint32_t x2 = __float_as_uint(v2), x3 = __float_as_uint(v3);
        uint2 hq, mq;
        hq.x = (x0>>16) | (x1 & 0xFFFF0000u);
        hq.y = (x2>>16) | (x3 & 0xFFFF0000u);
        float r0 = v0 - __uint_as_float(x0 & 0xFFFF0000u);
        float r1 = v1 - __uint_as_float(x1 & 0xFFFF0000u);
        float r2 = v2 - __uint_as_float(x2 & 0xFFFF0000u);
        float r3 = v3 - __uint_as_float(x3 & 0xFFFF0000u);
        mq.x = (__float_as_uint(r0)>>16) | (__float_as_uint(r1) & 0xFFFF0000u);
        mq.y = (__float_as_uint(r2)>>16) | (__float_as_uint(r3) & 0xFFFF0000u);
        *(uint2*)&sApl[baseown + 4*i]          = hq;
        *(uint2*)&sApl[APLANE + baseown + 4*i] = mq;
      }
    }
    __syncthreads();   // B1

    // ---- phase 2: next-iter eps (wave 3 only, overlapped) + MFMA GEMM ----
    if (wv == 3 && t < 98 && lane < MCAND){
      uint32_t kk0 = sKeys[2*t], kk1 = sKeys[2*t+1];
      uint32_t gidx = (uint32_t)b*MCAND + (uint32_t)lane;
      uint32_t r0,r1,bits;
      if (gidx < 102400u){ tf2x32(kk0,kk1,gidx,gidx+102400u,r0,r1); bits = r0; }
      else               { tf2x32(kk0,kk1,gidx-102400u,gidx,r0,r1); bits = r1; }
      float fl = __uint_as_float((bits>>9) | 0x3f800000u) - 1.0f;
      float u  = fmaxf(MINV, fl*2.0f + MINV);
      sEps[lane] = SQRT2 * erfinv32(u);
    }

    {
      f32x16 acc0, acc1;
#pragma unroll
      for (int r = 0; r < 16; ++r){ acc0[r] = 0.0f; acc1[r] = 0.0f; }

#pragma unroll
      for (int ks = 0; ks < 7; ++ks){
        const int kb = ks*16 + half*8;
        const int r0 = col*AROW + kb;
        const int r1 = (32+col)*AROW + kb;
        bf16x8 a0h = *(const bf16x8*)&sApl[r0];
        bf16x8 a1h = *(const bf16x8*)&sApl[r1];
        bf16x8 a0m = *(const bf16x8*)&sApl[APLANE + r0];
        bf16x8 a1m = *(const bf16x8*)&sApl[APLANE + r1];
        // hh + hm + mh (mm dropped: <=2^-18 rel, below 2-plane truncation noise)
        acc0 = MFMA(a0h, Bfh[ks], acc0);
        acc1 = MFMA(a1h, Bfh[ks], acc1);
        acc0 = MFMA(a0h, Bfm[ks], acc0);
        acc1 = MFMA(a1h, Bfm[ks], acc1);
        acc0 = MFMA(a0m, Bfh[ks], acc0);
        acc1 = MFMA(a1m, Bfh[ks], acc1);
      }

      // epilogue IN-PLACE on acc (dead after this; re-zeroed next iter):
      // h2 = relu(acc+b2[n]); qpart = h2*W3[n]
#pragma unroll
      for (int r = 0; r < 16; ++r){
        acc0[r] = fmaxf(acc0[r] + bn2, 0.0f) * wn3;
        acc1[r] = fmaxf(acc1[r] + bn2, 0.0f) * wn3;
      }
      // concentrated reduction over 32 columns: reg halving each step
#pragma unroll
      for (int step = 0; step < 4; ++step){
        const int off = 1 << step;
        const bool hi = (col & off) != 0;
        const int nn = 16 >> step;
#pragma unroll
        for (int i = 0; i < nn/2; ++i){
          float a0 = acc0[2*i]   + __shfl_xor(acc0[2*i],   off, 64);
          float b0 = acc0[2*i+1] + __shfl_xor(acc0[2*i+1], off, 64);
          acc0[i] = hi ? b0 : a0;
          float a1 = acc1[2*i]   + __shfl_xor(acc1[2*i],   off, 64);
          float b1_ = acc1[2*i+1] + __shfl_xor(acc1[2*i+1], off, 64);
          acc1[i] = hi ? b1_ : a1;
        }
      }
      float red0 = acc0[0] + __shfl_xor(acc0[0], 16, 64);
      float red1 = acc1[0] + __shfl_xor(acc1[0], 16, 64);
      const int c15 = col & 15;
      const int row = (c15 & 3) + 8*(c15 >> 2) + 4*half;
      if (col < 16) qbuf[wv][row]      = red0;
      else          qbuf[wv][row + 32] = red1;
    }
    __syncthreads();   // B2

    // ---- phase 3 (redundant on all 4 waves): partial-bitonic top-32 stats ----
    {
      float q = -INFINITY;
      if (lane < MCAND)
        q = qbuf[0][lane] + qbuf[1][lane] + qbuf[2][lane] + qbuf[3][lane] + sB3;
      // sort 32-halves in opposite directions (desc || asc = bitonic), then one
      // j=32 max-merge: lanes 0-31 hold the top-32 MULTISET (order irrelevant;
      // ties value-identical so unstable selection matches top_k's multiset)
      float v = q;
#pragma unroll
      for (int k = 2; k <= 32; k <<= 1){
#pragma unroll
        for (int j = k >> 1; j >= 1; j >>= 1){
          float pv = __shfl_xor(v, j, 64);
          bool lower = (lane & j) == 0;
          bool asc   = (lane & k) != 0;
          float mn = fminf(v, pv), mx = fmaxf(v, pv);
          v = (lower == asc) ? mn : mx;
        }
      }
      {
        float pv = __shfl_xor(v, 32, 64);
        v = ((lane & 32) == 0) ? fmaxf(v, pv) : fminf(v, pv);
      }
      float sv = (lane < NTOP) ? v : 0.0f;
#pragma unroll
      for (int off = 32; off >= 1; off >>= 1) sv += __shfl_xor(sv, off, 64);
      float mun = sv / 32.0f;
      float dv = (lane < NTOP) ? (v - mun) : 0.0f;
      float s2 = dv*dv;
#pragma unroll
      for (int off = 32; off >= 1; off >>= 1) s2 += __shfl_xor(s2, off, 64);
      stdv = sqrtf(s2 / 31.0f);
      mu = mun;
      if (t == 98 && tid == 0) out[b] = mu * 6.2831854820251465f;  // fp32(2*pi)
    }
    // no barrier: phase1(t+1) writes sApl race only vs phase2(t) reads (behind B2);
    // qbuf/sEps next written in phase2(t+1), behind B1(t+1).
  }
}

extern "C" void kernel_launch(void* const* d_in, const int* in_sizes, int n_in,
                              void* d_out, int out_size, void* d_ws, size_t ws_size,
                              hipStream_t stream) {
  const float* states = (const float*)d_in[0];
  const float* W1     = (const float*)d_in[1];
  const float* b1     = (const float*)d_in[2];
  const float* W2     = (const float*)d_in[3];
  const float* b2     = (const float*)d_in[4];
  const float* W3     = (const float*)d_in[5];
  const float* b3     = (const float*)d_in[6];
  float* out = (float*)d_out;
  hipLaunchKernelGGL(cem_kernel, dim3(BATCH), dim3(256), 0, stream,
                     states, W1, b1, W2, b2, W3, b3, out);
}

// Round 7
// 2529.250 us; speedup vs baseline: 3.9189x; 1.0105x over previous
//
#include <hip/hip_runtime.h>
#include <math.h>
#include <stdint.h>

#define BATCH 4096
#define MCAND 50
#define NTOP 32
#define HID 100

typedef __attribute__((ext_vector_type(8))) short bf16x8;
typedef __attribute__((ext_vector_type(16))) float f32x16;

union FragU { bf16x8 v; unsigned short s[8]; };

__device__ __forceinline__ uint32_t rotl32(uint32_t v, int d){ return (v<<d)|(v>>(32-d)); }

// JAX threefry2x32 core (20 rounds, 5 key injections)
__device__ __forceinline__ void tf2x32(uint32_t k0, uint32_t k1, uint32_t x0, uint32_t x1,
                                       uint32_t &o0, uint32_t &o1){
  uint32_t k2 = k0 ^ k1 ^ 0x1BD11BDAu;
  x0 += k0; x1 += k1;
#define RND(r) { x0 += x1; x1 = rotl32(x1,(r)); x1 ^= x0; }
  RND(13) RND(15) RND(26) RND(6)
  x0 += k1; x1 += k2 + 1u;
  RND(17) RND(29) RND(16) RND(24)
  x0 += k2; x1 += k0 + 2u;
  RND(13) RND(15) RND(26) RND(6)
  x0 += k0; x1 += k1 + 3u;
  RND(17) RND(29) RND(16) RND(24)
  x0 += k1; x1 += k2 + 4u;
  RND(13) RND(15) RND(26) RND(6)
  x0 += k2; x1 += k0 + 5u;
#undef RND
  o0 = x0; o1 = x1;
}

// XLA ErfInv32 (Giles). w = -log1p(-x*x)
__device__ __forceinline__ float erfinv32(float x){
  float w = -log1pf(-x*x);
  float p;
  if (w < 5.0f){
    w = w - 2.5f;
    p = 2.81022636e-08f;
    p = fmaf(p, w, 3.43273939e-07f);
    p = fmaf(p, w, -3.5233877e-06f);
    p = fmaf(p, w, -4.39150654e-06f);
    p = fmaf(p, w, 0.00021858087f);
    p = fmaf(p, w, -0.00125372503f);
    p = fmaf(p, w, -0.00417768164f);
    p = fmaf(p, w, 0.246640727f);
    p = fmaf(p, w, 1.50140941f);
  } else {
    w = sqrtf(w) - 3.0f;
    p = -0.000200214257f;
    p = fmaf(p, w, 0.000100950558f);
    p = fmaf(p, w, 0.00134934322f);
    p = fmaf(p, w, -0.00367342844f);
    p = fmaf(p, w, 0.00573950773f);
    p = fmaf(p, w, -0.0076224613f);
    p = fmaf(p, w, 0.00943887047f);
    p = fmaf(p, w, 1.00167406f);
    p = fmaf(p, w, 2.83297682f);
  }
  return p*x;
}

// 2-plane bf16 split (truncation): x ~= h+m with rel error <= 2^-16
__device__ __forceinline__ void split2(float x, unsigned short &h, unsigned short &m){
  uint32_t xb = __float_as_uint(x);
  h = (unsigned short)(xb >> 16);
  float r = x - __uint_as_float(xb & 0xFFFF0000u);
  m = (unsigned short)(__float_as_uint(r) >> 16);
}

#define MFMA(a,b,c) __builtin_amdgcn_mfma_f32_32x32x16_bf16((a),(b),(c),0,0,0)

// LDS A-planes: 2 planes x 64 rows x 104 bf16 (208B rows; word-step 52 == 20 mod 32)
#define AROW 104
#define APLANE (64*AROW)

__global__ __launch_bounds__(256, 3) void cem_kernel(
    const float* __restrict__ states, const float* __restrict__ W1,
    const float* __restrict__ b1,     const float* __restrict__ W2,
    const float* __restrict__ b2,     const float* __restrict__ W3,
    const float* __restrict__ b3,     float* __restrict__ out)
{
  __shared__ __align__(16) unsigned short sApl[2*APLANE]; // 26624 B
  __shared__ float qbuf[2][64];
  __shared__ __align__(16) float sSW[HID];
  __shared__ __align__(16) float sW13[HID];
  __shared__ float sEps[64];
  __shared__ uint32_t sKeys[198];
  __shared__ float sB3;

  const int tid  = threadIdx.x;
  const int b    = blockIdx.x;
  const int wv   = tid >> 6;
  const int lane = tid & 63;
  const int half = lane >> 5;
  const int col  = lane & 31;
  // wave role: one M-tile (32 candidate rows), one N-pair (2 x 32 output cols)
  const int mt   = wv >> 1;            // 0,0,1,1
  const int np   = wv & 1;             // 0,1,0,1
  const int n0   = (2*np)*32 + col;
  const int n1   = (2*np+1)*32 + col;

  const float s0 = states[2*b], s1 = states[2*b+1];

  // zero-init A planes (pads must stay zero)
  for (int f = tid; f < APLANE; f += 256) ((unsigned int*)sApl)[f] = 0u;

  if (tid < HID){
    float w0 = W1[tid], w1 = W1[HID+tid];
    sSW[tid]  = fmaf(s0, w0, fmaf(s1, w1, b1[tid]));
    sW13[tid] = W1[2*HID+tid];
  }
  if (tid == 0) sB3 = b3[0];

  // per-lane epilogue constants (two N-tiles per wave)
  const float bn2_0 = (n0 < HID) ? b2[n0] : 0.0f;
  const float wn3_0 = (n0 < HID) ? W3[n0] : 0.0f;
  const float bn2_1 = (n1 < HID) ? b2[n1] : 0.0f;
  const float wn3_1 = (n1 < HID) ? W3[n1] : 0.0f;

  // one-time: static W2 B-fragments in registers (2-plane bf16 split), 2 N-tiles
  bf16x8 Bfh[2][7], Bfm[2][7];
#pragma unroll
  for (int j = 0; j < 2; ++j){
    const int n = j ? n1 : n0;
#pragma unroll
    for (int ks = 0; ks < 7; ++ks){
      FragU fh, fm;
#pragma unroll
      for (int i = 0; i < 8; ++i){
        int k = ks*16 + half*8 + i;
        float w = (k < HID && n < HID) ? W2[k*HID + n] : 0.0f;
        split2(w, fh.s[i], fm.s[i]);
      }
      Bfh[j][ks] = fh.v; Bfm[j][ks] = fm.v;
    }
  }

  // phase-1 fixed ownership: thread -> (candidate c_own, 20-wide k strip)
  const bool p1act = (tid < 250);
  const int  c_own = tid / 5;            // hoisted division (once)
  const int  k0own = (tid - c_own*5) * 20;
  const int  baseown = c_own*AROW + k0own;

  // key schedule: key(42) = (0,42); split -> k0=(A0,B0), kloop=(A1,B1)
  if (tid < 99){
    uint32_t A0,A1,B0,B1;
    tf2x32(0u,42u,0u,2u,A0,A1);
    tf2x32(0u,42u,1u,3u,B0,B1);
    uint32_t o0,o1;
    tf2x32(A1,B1,(uint32_t)tid,(uint32_t)(99+tid),o0,o1);
    sKeys[tid]    = o0;
    sKeys[99+tid] = o1;
    if (tid < MCAND){
      // iteration-0 "eps" = uniform angles (mu=0, std=1 makes a_c = eps_c)
      uint32_t gidx = (uint32_t)b*MCAND + (uint32_t)tid;
      uint32_t r0,r1,bits;
      if (gidx < 102400u){ tf2x32(A0,B0,gidx,gidx+102400u,r0,r1); bits = r0; }
      else               { tf2x32(A0,B0,gidx-102400u,gidx,r0,r1); bits = r1; }
      sEps[tid] = __uint_as_float((bits>>9) | 0x3f800000u) - 1.0f;
    }
  }
  __syncthreads();

  const float MINV = -0x1.fffffep-1f;   // nextafter(-1,0)
  const float SQRT2 = 0x1.6a09e6p+0f;   // fp32 sqrt(2)

  float mu = 0.0f, stdv = 1.0f;         // per-wave redundant CEM state

#pragma unroll 1
  for (int t = 0; t < 99; ++t){
    // ---- phase 1: a_c = mu + std*eps_c; h1 = relu(sSW + a_c*sW13); split2 to LDS ----
    if (p1act){
      const float a = fmaf(stdv, sEps[c_own], mu);
#pragma unroll
      for (int i = 0; i < 5; ++i){
        const int k = k0own + 4*i;
        float4 sw  = *(const float4*)&sSW[k];
        float4 w13 = *(const float4*)&sW13[k];
        float v0 = fmaxf(fmaf(a, w13.x, sw.x), 0.0f);
        float v1 = fmaxf(fmaf(a, w13.y, sw.y), 0.0f);
        float v2 = fmaxf(fmaf(a, w13.z, sw.z), 0.0f);
        float v3 = fmaxf(fmaf(a, w13.w, sw.w), 0.0f);
        uint32_t x0 = __float_as_uint(v0), x1 = __float_as_uint(v1);
        uint32_t x2 = __float_as_uint(v2), x3 = __float_as_uint(v3);
        uint2 hq, mq;
        hq.x = (x0>>16) | (x1 & 0xFFFF0000u);
        hq.y = (x2>>16) | (x3 & 0xFFFF0000u);
        float r0 = v0 - __uint_as_float(x0 & 0xFFFF0000u);
        float r1 = v1 - __uint_as_float(x1 & 0xFFFF0000u);
        float r2 = v2 - __uint_as_float(x2 & 0xFFFF0000u);
        float r3 = v3 - __uint_as_float(x3 & 0xFFFF0000u);
        mq.x = (__float_as_uint(r0)>>16) | (__float_as_uint(r1) & 0xFFFF0000u);
        mq.y = (__float_as_uint(r2)>>16) | (__float_as_uint(r3) & 0xFFFF0000u);
        *(uint2*)&sApl[baseown + 4*i]          = hq;
        *(uint2*)&sApl[APLANE + baseown + 4*i] = mq;
      }
    }
    __syncthreads();   // B1

    // ---- phase 2: next-iter eps (wave 3 only, overlapped) + MFMA GEMM ----
    if (wv == 3 && t < 98 && lane < MCAND){
      uint32_t kk0 = sKeys[2*t], kk1 = sKeys[2*t+1];
      uint32_t gidx = (uint32_t)b*MCAND + (uint32_t)lane;
      uint32_t r0,r1,bits;
      if (gidx < 102400u){ tf2x32(kk0,kk1,gidx,gidx+102400u,r0,r1); bits = r0; }
      else               { tf2x32(kk0,kk1,gidx-102400u,gidx,r0,r1); bits = r1; }
      float fl = __uint_as_float((bits>>9) | 0x3f800000u) - 1.0f;
      float u  = fmaxf(MINV, fl*2.0f + MINV);
      sEps[lane] = SQRT2 * erfinv32(u);
    }

    {
      f32x16 acc0, acc1;   // two N-tiles, same M-tile
#pragma unroll
      for (int r = 0; r < 16; ++r){ acc0[r] = 0.0f; acc1[r] = 0.0f; }

#pragma unroll
      for (int ks = 0; ks < 7; ++ks){
        const int kb = ks*16 + half*8;
        const int ra = (mt*32 + col)*AROW + kb;
        bf16x8 ah = *(const bf16x8*)&sApl[ra];
        bf16x8 am = *(const bf16x8*)&sApl[APLANE + ra];
        // hh + hm + mh per N-tile (mm dropped: below 2-plane truncation noise)
        acc0 = MFMA(ah, Bfh[0][ks], acc0);
        acc1 = MFMA(ah, Bfh[1][ks], acc1);
        acc0 = MFMA(ah, Bfm[0][ks], acc0);
        acc1 = MFMA(ah, Bfm[1][ks], acc1);
        acc0 = MFMA(am, Bfh[0][ks], acc0);
        acc1 = MFMA(am, Bfh[1][ks], acc1);
      }

      // epilogue: per-N-tile relu+W3 scale, then SUM the two N-tiles
      // elementwise (same candidates!) -> single 32-col reduction
      float v[16];
#pragma unroll
      for (int r = 0; r < 16; ++r){
        v[r] = fmaxf(acc0[r] + bn2_0, 0.0f) * wn3_0
             + fmaxf(acc1[r] + bn2_1, 0.0f) * wn3_1;
      }
      // concentrated reduction over 32 columns: reg halving each step
#pragma unroll
      for (int step = 0; step < 4; ++step){
        const int off = 1 << step;
        const bool hi = (col & off) != 0;
        const int nn = 16 >> step;
#pragma unroll
        for (int i = 0; i < nn/2; ++i){
          float a0 = v[2*i]   + __shfl_xor(v[2*i],   off, 64);
          float b0 = v[2*i+1] + __shfl_xor(v[2*i+1], off, 64);
          v[i] = hi ? b0 : a0;
        }
      }
      float red = v[0] + __shfl_xor(v[0], 16, 64);
      const int c15 = col & 15;
      const int row = (c15 & 3) + 8*(c15 >> 2) + 4*half;
      if (col < 16) qbuf[np][mt*32 + row] = red;
    }
    __syncthreads();   // B2

    // ---- phase 3 (redundant on all 4 waves): partial-bitonic top-32 stats ----
    {
      float q = -INFINITY;
      if (lane < MCAND)
        q = qbuf[0][lane] + qbuf[1][lane] + sB3;
      // sort 32-halves in opposite directions (desc || asc = bitonic), then one
      // j=32 max-merge: lanes 0-31 hold the top-32 MULTISET (ties value-identical)
      float v = q;
#pragma unroll
      for (int k = 2; k <= 32; k <<= 1){
#pragma unroll
        for (int j = k >> 1; j >= 1; j >>= 1){
          float pv = __shfl_xor(v, j, 64);
          bool lower = (lane & j) == 0;
          bool asc   = (lane & k) != 0;
          float mn = fminf(v, pv), mx = fmaxf(v, pv);
          v = (lower == asc) ? mn : mx;
        }
      }
      {
        float pv = __shfl_xor(v, 32, 64);
        v = ((lane & 32) == 0) ? fmaxf(v, pv) : fminf(v, pv);
      }
      float sv = (lane < NTOP) ? v : 0.0f;
#pragma unroll
      for (int off = 32; off >= 1; off >>= 1) sv += __shfl_xor(sv, off, 64);
      float mun = sv / 32.0f;
      float dv = (lane < NTOP) ? (v - mun) : 0.0f;
      float s2 = dv*dv;
#pragma unroll
      for (int off = 32; off >= 1; off >>= 1) s2 += __shfl_xor(s2, off, 64);
      stdv = sqrtf(s2 / 31.0f);
      mu = mun;
      if (t == 98 && tid == 0) out[b] = mu * 6.2831854820251465f;  // fp32(2*pi)
    }
    // no barrier: phase1(t+1) writes sApl race only vs phase2(t) reads (behind B2);
    // qbuf/sEps next written in phase2(t+1), behind B1(t+1).
  }
}

extern "C" void kernel_launch(void* const* d_in, const int* in_sizes, int n_in,
                              void* d_out, int out_size, void* d_ws, size_t ws_size,
                              hipStream_t stream) {
  const float* states = (const float*)d_in[0];
  const float* W1     = (const float*)d_in[1];
  const float* b1     = (const float*)d_in[2];
  const float* W2     = (const float*)d_in[3];
  const float* b2     = (const float*)d_in[4];
  const float* W3     = (const float*)d_in[5];
  const float* b3     = (const float*)d_in[6];
  float* out = (float*)d_out;
  hipLaunchKernelGGL(cem_kernel, dim3(BATCH), dim3(256), 0, stream,
                     states, W1, b1, W2, b2, W3, b3, out);
}